// Round 3
// baseline (442.491 us; speedup 1.0000x reference)
//
#include <hip/hip_runtime.h>

// RaggedSelectThreshold, single-dispatch decoupled-lookback implementation.
// Keep rows with xs > 0.5; stably compact pl rows to front of [N,F] buffer
// (zero-padded); emit new row splits and scatter idxs (padded with N).
// d_out (floats): [N*F newfeat][B+1 new_rs][N scatter_idxs]
// d_ws: [int ticket][unsigned status[nblocks]]  (memset to 0 at launch; flag
//        encoding: bits31:30 = 0 invalid / 1 aggregate / 2 inclusive, 29:0 value)

#define THRESH 0.5f
#define RPB 1024   // rows per tile (4 chunks of 256 threads)

__global__ __launch_bounds__(256, 4)   // >=4 blocks/CU -> all 782 tiles co-resident
void k_all(const float* __restrict__ xs, const float4* __restrict__ pl4,
           const int* __restrict__ rs, int nrs, int N, int nblocks,
           int* __restrict__ ticket, unsigned* __restrict__ status,
           float4* __restrict__ outf4, float* __restrict__ out_rs,
           float* __restrict__ out_sc) {
    __shared__ int s_t;
    __shared__ unsigned long long w[16];   // mask bitmap for this tile
    __shared__ int wpre[17];               // exclusive prefix of word popcounts
    __shared__ int s_off, s_nsel;
    __shared__ int rowid[RPB];             // input row per local compacted slot

    const int tid  = threadIdx.x;
    const int lane = tid & 63, wave = tid >> 6;

    if (tid == 0) s_t = atomicAdd(ticket, 1);   // dispatch-start-ordered tile id
    __syncthreads();
    const int t    = s_t;
    const int base = t << 10;
    const int end  = min(base + RPB, N);

    // ---- phase 1: ballot mask -> LDS words; publish aggregate early ----
    for (int c = 0; c < 4; ++c) {
        int i = base + c * 256 + tid;
        int m = (i < N) && (xs[i] > THRESH);
        unsigned long long bal = __ballot(m);
        if (lane == 0) w[c * 4 + wave] = bal;
    }
    __syncthreads();
    if (tid == 0) {
        int acc = 0;
        for (int k = 0; k < 16; ++k) { wpre[k] = acc; acc += __popcll(w[k]); }
        wpre[16] = acc;
        unsigned flag = (t == 0) ? 2u : 1u;   // tile 0's aggregate IS its inclusive
        __hip_atomic_store(&status[t], (flag << 30) | (unsigned)acc,
                           __ATOMIC_RELEASE, __HIP_MEMORY_SCOPE_AGENT);
    }
    __syncthreads();
    const int cnt = wpre[16];

    // ---- phase 2: decoupled lookback (wave 0), 64 predecessors per round ----
    if (wave == 0) {
        int excl = 0;
        if (t > 0) {
            int idx = t - 1;
            for (;;) {
                int my = idx - lane;
                unsigned st = 2u << 30;          // virtual inclusive 0 for my < 0
                bool done = (my < 0);
                while (__ballot(!done)) {
                    if (!done) {
                        st = __hip_atomic_load(&status[my], __ATOMIC_ACQUIRE,
                                               __HIP_MEMORY_SCOPE_AGENT);
                        done = (st >> 30) != 0u;
                    }
                }
                unsigned long long incl = __ballot((st >> 30) == 2u);
                int firstIncl = (incl != 0ull) ? (__ffsll((unsigned long long)incl) - 1) : 64;
                int val = (lane <= firstIncl) ? (int)(st & 0x3FFFFFFFu) : 0;
                for (int o = 32; o > 0; o >>= 1) val += __shfl_down(val, o, 64);
                excl += __shfl(val, 0, 64);
                if (incl != 0ull) break;
                idx -= 64;
            }
        }
        if (lane == 0) {
            s_off = excl;
            __hip_atomic_store(&status[t], (2u << 30) | (unsigned)(excl + cnt),
                               __ATOMIC_RELEASE, __HIP_MEMORY_SCOPE_AGENT);
        }
    }
    __syncthreads();
    const int off = s_off;

    // ---- phase 3: scatter indices + local compaction map ----
    for (int c = 0; c < 4; ++c) {
        int r = c * 256 + tid;
        int i = base + r;
        int k = r >> 6, bit = r & 63;
        unsigned long long bw = w[k];
        if (i < N && ((bw >> bit) & 1ull)) {
            int pre = wpre[k] + (int)__popcll(bw & ((1ull << bit) - 1ull));
            rowid[pre] = i;
            out_sc[off + pre] = (float)i;
        }
    }

    // ---- new row splits: owning tile computes prefix at boundary ----
    if (tid < nrs) {
        int j = rs[tid];
        bool mine = (j == 0) ? (t == 0) : (j > base && j <= end);
        if (mine) {
            int val;
            if (j == 0) val = 0;
            else {
                int d = j - base;                  // 1..1024
                if (d == RPB) val = off + cnt;
                else {
                    int k = d >> 6, rem = d & 63;
                    val = off + wpre[k] +
                          (rem ? (int)__popcll(w[k] & ((1ull << rem) - 1ull)) : 0);
                }
            }
            out_rs[tid] = (float)val;              // int value as f32 (exact < 2^24)
        }
    }
    __syncthreads();   // rowid ready

    // ---- phase 4: payload copy for selected rows (float4, 16 lanes/row) ----
    const int cc = tid & 15;
    for (int p = tid >> 4; p < cnt; p += 16) {
        int src = rowid[p];
        outf4[(size_t)(off + p) * 16 + cc] = pl4[(size_t)src * 16 + cc];
    }

    // ---- phase 5: wait for global n_sel (last tile's inclusive), then pad ----
    if (tid == 0) {
        unsigned st;
        do {
            st = __hip_atomic_load(&status[nblocks - 1], __ATOMIC_ACQUIRE,
                                   __HIP_MEMORY_SCOPE_AGENT);
        } while ((st >> 30) != 2u);
        s_nsel = (int)(st & 0x3FFFFFFFu);
    }
    __syncthreads();
    const int nsel  = s_nsel;
    const int u_pre = base - off;          // unselected rows before this tile
    const int u     = (end - base) - cnt;  // unselected rows in this tile
    // this tile owns output slots [nsel + u_pre, nsel + u_pre + u)
    for (int p = tid; p < u; p += 256) out_sc[nsel + u_pre + p] = (float)N;
    const float4 z = make_float4(0.f, 0.f, 0.f, 0.f);
    for (int p = tid >> 4; p < u; p += 16)
        outf4[(size_t)(nsel + u_pre + p) * 16 + cc] = z;
}

extern "C" void kernel_launch(void* const* d_in, const int* in_sizes, int n_in,
                              void* d_out, int out_size, void* d_ws, size_t ws_size,
                              hipStream_t stream) {
    const float* xs = (const float*)d_in[0];
    const float* pl = (const float*)d_in[1];
    const int*   rs = (const int*)d_in[2];
    const int N   = in_sizes[0];        // 800000
    const int F   = in_sizes[1] / N;    // 64 (kernel assumes 64)
    const int nrs = in_sizes[2];        // B+1 = 9

    float* out      = (float*)d_out;
    float* out_feat = out;
    float* out_rs   = out + (size_t)N * F;
    float* out_sc   = out_rs + nrs;

    int*      ticket = (int*)d_ws;
    unsigned* status = (unsigned*)d_ws + 1;

    const int nblocks = (N + RPB - 1) / RPB;   // 782 (<= 1024 co-resident slots)

    // d_ws is poisoned to 0xAA (flag bits would read "inclusive") -> zero it.
    hipMemsetAsync(d_ws, 0, (size_t)(nblocks + 1) * sizeof(int), stream);

    k_all<<<nblocks, 256, 0, stream>>>(xs, (const float4*)pl, rs, nrs, N, nblocks,
                                       ticket, status, (float4*)out_feat,
                                       out_rs, out_sc);
}